// Round 1
// baseline (1014.074 us; speedup 1.0000x reference)
//
#include <hip/hip_runtime.h>

#define BB 512
#define TT 1024
#define DX 32
#define DZ 64
#define DY 256
#define ALPHA 0.125f

// One block per batch element. 256 threads.
// Thread tid: owns hidden[y=tid] (W2 row in regs) and partial z (z=tid&63,
// chunk g=tid>>6, W1[z][g*64..] in regs).
// 3 barriers/step; LDS reads are wave-uniform broadcasts (free) or 2-way
// aliased (free on gfx950 per m136).
__global__ __launch_bounds__(256, 2)
void plrnn_scan(const float* __restrict__ X, const float* __restrict__ A,
                const float* __restrict__ W1, const float* __restrict__ W2,
                const float* __restrict__ h1, const float* __restrict__ h2,
                float* __restrict__ out) {
    const int b   = blockIdx.x;
    const int tid = threadIdx.x;
    const int z   = tid & 63;
    const int g   = tid >> 6;

    __shared__ float zf_s[DZ];
    __shared__ float hid_s[DY];
    __shared__ float part_s[256];

    // --- stage weights into registers (one-time) ---
    float4 w2[16];  // W2[y=tid][0..63]
    float4 w1[16];  // W1[z][g*64 .. g*64+63]
    const float4* W2v = (const float4*)(W2 + tid * DZ);
    const float4* W1v = (const float4*)(W1 + z * DY + g * 64);
#pragma unroll
    for (int i = 0; i < 16; ++i) w2[i] = W2v[i];
#pragma unroll
    for (int i = 0; i < 16; ++i) w1[i] = W1v[i];

    const float h2r = h2[tid];
    const float Ar  = A[z];
    const float h1r = h1[z];

    const float* Xb = X   + (size_t)b * TT * DX;
    float*       Ob = out + (size_t)b * TT * DX;

    // --- z0 = teacher_force(zeros, X[:,0], alpha=1) ---
    float zreg = 0.0f;  // live only for tid < 64
    float xcur = 0.0f;  // raw forcing value for current t (may be NaN)
    if (tid < DX) {
        float x0 = Xb[tid];
        xcur = x0;
        zreg = (x0 == x0) ? x0 : 0.0f;
    }

    for (int t = 0; t < TT; ++t) {
        // prefetch next forcing value (hide HBM/L2 latency behind the step)
        float xnext = 0.0f;
        if (tid < DX && t + 1 < TT) xnext = Xb[(t + 1) * DX + tid];

        // teacher-forced blend into first DX dims
        float zf = zreg;
        if (tid < DZ) {
            if (z < DX) {
                float f = xcur;
                zf = (f == f) ? fmaf(ALPHA, f, (1.0f - ALPHA) * zreg) : zreg;
            }
            zf_s[z] = zf;
        }
        __syncthreads();

        // hidden[y=tid] = relu(W2[y] . zf + h2[y])
        float acc = h2r;
        const float4* zf4 = (const float4*)zf_s;
#pragma unroll
        for (int i = 0; i < 16; ++i) {
            float4 v = zf4[i];      // wave-uniform broadcast
            acc = fmaf(w2[i].x, v.x, acc);
            acc = fmaf(w2[i].y, v.y, acc);
            acc = fmaf(w2[i].z, v.z, acc);
            acc = fmaf(w2[i].w, v.w, acc);
        }
        hid_s[tid] = fmaxf(acc, 0.0f);
        __syncthreads();

        // partial of z_new[z] over y-chunk g
        float part = 0.0f;
        const float4* h4 = (const float4*)(hid_s + g * 64);
#pragma unroll
        for (int i = 0; i < 16; ++i) {
            float4 v = h4[i];       // wave-uniform broadcast (g uniform per wave)
            part = fmaf(w1[i].x, v.x, part);
            part = fmaf(w1[i].y, v.y, part);
            part = fmaf(w1[i].z, v.z, part);
            part = fmaf(w1[i].w, v.w, part);
        }
        part_s[tid] = part;
        __syncthreads();

        // reduce 4 partials, finish z_new, emit output
        if (tid < DZ) {
            float s = part_s[z] + part_s[z + 64] + part_s[z + 128] + part_s[z + 192];
            zreg = fmaf(Ar, zf, s + h1r);
            if (z < DX) Ob[t * DX + z] = zreg;
        }
        xcur = xnext;
    }
}

extern "C" void kernel_launch(void* const* d_in, const int* in_sizes, int n_in,
                              void* d_out, int out_size, void* d_ws, size_t ws_size,
                              hipStream_t stream) {
    const float* X  = (const float*)d_in[0];
    const float* A  = (const float*)d_in[1];
    const float* W1 = (const float*)d_in[2];
    const float* W2 = (const float*)d_in[3];
    const float* h1 = (const float*)d_in[4];
    const float* h2 = (const float*)d_in[5];
    float* out = (float*)d_out;

    plrnn_scan<<<BB, 256, 0, stream>>>(X, A, W1, W2, h1, h2, out);
}